// Round 2
// baseline (409.396 us; speedup 1.0000x reference)
//
#include <hip/hip_runtime.h>

typedef unsigned short u16;
typedef u16 u16x8 __attribute__((ext_vector_type(8)));
typedef u16 u16x4 __attribute__((ext_vector_type(4)));
typedef float f32x4 __attribute__((ext_vector_type(4)));
typedef __bf16 bf16x8 __attribute__((ext_vector_type(8)));

#define SCALE_ 0.125f

__device__ __forceinline__ u16 f2bf(float f) {
  union { float f; unsigned u; } v; v.f = f;
  unsigned r = (v.u + 0x7FFFu + ((v.u >> 16) & 1u)) >> 16;
  return (u16)r;
}

__device__ __forceinline__ void gl_lds16(const void* g, void* l) {
  __builtin_amdgcn_global_load_lds(
      (const __attribute__((address_space(1))) void*)g,
      (__attribute__((address_space(3))) void*)l, 16, 0, 0);
}

// ---------------- cast fp32 -> bf16, 8 elems/thread ----------------
__global__ __launch_bounds__(256) void cast_f32_bf16(const float* __restrict__ in,
                                                     u16* __restrict__ out) {
  long i = ((long)blockIdx.x * 256 + threadIdx.x) * 8;
  f32x4 a = *(const f32x4*)(in + i);
  f32x4 b = *(const f32x4*)(in + i + 4);
  u16x8 o;
  o[0] = f2bf(a[0]); o[1] = f2bf(a[1]); o[2] = f2bf(a[2]); o[3] = f2bf(a[3]);
  o[4] = f2bf(b[0]); o[5] = f2bf(b[1]); o[6] = f2bf(b[2]); o[7] = f2bf(b[3]);
  *(u16x8*)(out + i) = o;
}

// ---------------- NT GEMM: C = A * B^T  (both row-major [rows][K=1024]) ----
// 128x128 tile, BK=32, 4 waves each owning a 64x64 quadrant (4x4 frags).
// MODE 0: bf16 out into qk [M][2048] for cols<2048; cols>=2048 go TRANSPOSED
//         into Vt[bh*64+d][2048] (fuses the V transpose).
// MODE 1: fp32 out [M][1024] + bias.
template<int MODE>
__global__ __launch_bounds__(256) void gemm_nt(
    const u16* __restrict__ A, const u16* __restrict__ Bw,
    u16* __restrict__ Cb, u16* __restrict__ Vt,
    float* __restrict__ Cf, const float* __restrict__ bias) {
  constexpr int K = 1024;
  __shared__ __align__(16) u16 sA[128 * 32];
  __shared__ __align__(16) u16 sB[128 * 32];
  const int t = threadIdx.x;
  const int w = t >> 6, l = t & 63;
  const int fr = l & 15, fg = l >> 4;
  const int bm = blockIdx.y * 128, bn = blockIdx.x * 128;
  const int wr = (w >> 1) << 6, wc = (w & 1) << 6;

  f32x4 acc[4][4] = {};

  const int tr = t >> 2, tc = (t & 3) * 8;  // staging: row t>>2, 8-elem chunk
  const u16* gA0 = A + (long)(bm + tr) * K + tc;
  const u16* gB0 = Bw + (long)(bn + tr) * K + tc;
  char* sAc = (char*)sA; char* sBc = (char*)sB;
  const int wb = w * 1024;  // wave-uniform LDS byte base

  for (int k0 = 0; k0 < K; k0 += 32) {
    gl_lds16(gA0 + k0,                 sAc + wb);
    gl_lds16(gA0 + (long)64 * K + k0,  sAc + 4096 + wb);
    gl_lds16(gB0 + k0,                 sBc + wb);
    gl_lds16(gB0 + (long)64 * K + k0,  sBc + 4096 + wb);
    __syncthreads();
    bf16x8 af[4], bf[4];
#pragma unroll
    for (int m = 0; m < 4; ++m)
      af[m] = *(const bf16x8*)&sA[(wr + m * 16 + fr) * 32 + fg * 8];
#pragma unroll
    for (int n = 0; n < 4; ++n)
      bf[n] = *(const bf16x8*)&sB[(wc + n * 16 + fr) * 32 + fg * 8];
#pragma unroll
    for (int m = 0; m < 4; ++m) {
#pragma unroll
      for (int n = 0; n < 4; ++n)
        acc[m][n] = __builtin_amdgcn_mfma_f32_16x16x32_bf16(af[m], bf[n], acc[m][n], 0, 0, 0);
    }
    __syncthreads();
  }

#pragma unroll
  for (int m = 0; m < 4; ++m) {
    const int grow = bm + wr + m * 16 + fg * 4;  // 4 consecutive rows grow..grow+3
#pragma unroll
    for (int n = 0; n < 4; ++n) {
      const int gcol = bn + wc + n * 16 + fr;
      if (MODE == 1) {
        float bv = bias[gcol];
#pragma unroll
        for (int r = 0; r < 4; ++r)
          Cf[(long)(grow + r) * 1024 + gcol] = acc[m][n][r] + bv;
      } else {
        if (bn < 2048) {
#pragma unroll
          for (int r = 0; r < 4; ++r)
            Cb[(long)(grow + r) * 2048 + gcol] = f2bf(acc[m][n][r]);
        } else {
          const int d = gcol - 2048;           // 0..1023 -> (h, dl)
          const int bb = grow >> 11, nn = grow & 2047;
          u16x4 pk;
#pragma unroll
          for (int r = 0; r < 4; ++r) pk[r] = f2bf(acc[m][n][r]);
          *(u16x4*)&Vt[((long)(bb * 16 + (d >> 6)) * 64 + (d & 63)) * 2048 + nn] = pk;
        }
      }
    }
  }
}

// ---------------- flash attention ----------------
// grid (32 q-tiles, 64 bh). 4 waves x 16 q-rows. KVBLK=64.
// qk: [B*N][2048] (Q cols 0..1023, K cols 1024..2047); vt: [bh*64+d][2048].
__global__ __launch_bounds__(256) void attn_fused(
    const u16* __restrict__ qk, const u16* __restrict__ vt,
    u16* __restrict__ ao) {
  const int t = threadIdx.x;
  const int w = t >> 6, l = t & 63;
  const int fr = l & 15, fg = l >> 4;
  const int q0 = blockIdx.x * 64;
  const int bh = blockIdx.y, b = bh >> 4, h = bh & 15;

  __shared__ __align__(16) u16 sK[2 * 64 * 32];   // [kk][kv 64][d-chunk 32]
  __shared__ __align__(16) u16 sV[2 * 64 * 32];   // [kc][d 64][kv-chunk 32]
  __shared__ __align__(16) u16 sP[4][16 * 72];    // per-wave P [16 q][72]

  // Q fragments (hoisted): rows q0+w*16+fr, d = fg*8+32*kk + j
  bf16x8 qf[2];
  {
    const u16* qb = qk + (long)(b * 2048 + q0 + w * 16 + fr) * 2048 + h * 64 + fg * 8;
    qf[0] = *(const bf16x8*)qb;
    qf[1] = *(const bf16x8*)(qb + 32);
  }

  f32x4 acc_o[4] = {};
  float mrow[4], lrow[4];
#pragma unroll
  for (int r = 0; r < 4; ++r) { mrow[r] = -__builtin_inff(); lrow[r] = 0.f; }

  const u16* gK = qk + (long)(b * 2048 + (t >> 2)) * 2048 + 1024 + h * 64 + (t & 3) * 8;
  const u16* gV = vt + (long)(bh * 64 + (t >> 2)) * 2048 + (t & 3) * 8;
  char* sKc = (char*)sK; char* sVc = (char*)sV;
  const int wb = w * 1024;
  u16* sPw = &sP[w][0];

  for (int kv0 = 0; kv0 < 2048; kv0 += 64) {
    gl_lds16(gK + (long)kv0 * 2048,      sKc + wb);
    gl_lds16(gK + (long)kv0 * 2048 + 32, sKc + 4096 + wb);
    gl_lds16(gV + kv0,                   sVc + wb);
    gl_lds16(gV + kv0 + 32,              sVc + 4096 + wb);
    __syncthreads();

    // S = Q K^T (16 x 64 per wave), fp32 acc
    f32x4 s[4] = {};
#pragma unroll
    for (int kk = 0; kk < 2; ++kk) {
#pragma unroll
      for (int t2 = 0; t2 < 4; ++t2) {
        bf16x8 kf = *(const bf16x8*)&sK[kk * 2048 + (t2 * 16 + fr) * 32 + fg * 8];
        s[t2] = __builtin_amdgcn_mfma_f32_16x16x32_bf16(qf[kk], kf, s[t2], 0, 0, 0);
      }
    }

    // online softmax per row (row = fg*4 + r; cols spread over 16-lane group)
    float al[4];
#pragma unroll
    for (int r = 0; r < 4; ++r) {
#pragma unroll
      for (int t2 = 0; t2 < 4; ++t2) s[t2][r] *= SCALE_;
      float v = fmaxf(fmaxf(s[0][r], s[1][r]), fmaxf(s[2][r], s[3][r]));
      v = fmaxf(v, __shfl_xor(v, 1));
      v = fmaxf(v, __shfl_xor(v, 2));
      v = fmaxf(v, __shfl_xor(v, 4));
      v = fmaxf(v, __shfl_xor(v, 8));
      float mn = fmaxf(mrow[r], v);
      al[r] = __expf(mrow[r] - mn);
      mrow[r] = mn;
      float rsum = 0.f;
#pragma unroll
      for (int t2 = 0; t2 < 4; ++t2) {
        float p = __expf(s[t2][r] - mn);
        s[t2][r] = p;
        rsum += p;
      }
      rsum += __shfl_xor(rsum, 1);
      rsum += __shfl_xor(rsum, 2);
      rsum += __shfl_xor(rsum, 4);
      rsum += __shfl_xor(rsum, 8);
      lrow[r] = lrow[r] * al[r] + rsum;
    }
#pragma unroll
    for (int tt = 0; tt < 4; ++tt) {
#pragma unroll
      for (int r = 0; r < 4; ++r) acc_o[tt][r] *= al[r];
    }

    // P -> per-wave LDS (transpose via LDS; same-wave, no barrier needed)
#pragma unroll
    for (int t2 = 0; t2 < 4; ++t2) {
#pragma unroll
      for (int r = 0; r < 4; ++r)
        sPw[(fg * 4 + r) * 72 + t2 * 16 + fr] = f2bf(s[t2][r]);
    }

    // O += P * V
#pragma unroll
    for (int kc = 0; kc < 2; ++kc) {
      bf16x8 pf = *(const bf16x8*)&sPw[fr * 72 + kc * 32 + fg * 8];
#pragma unroll
      for (int tt = 0; tt < 4; ++tt) {
        bf16x8 vf = *(const bf16x8*)&sV[kc * 2048 + (tt * 16 + fr) * 32 + fg * 8];
        acc_o[tt] = __builtin_amdgcn_mfma_f32_16x16x32_bf16(pf, vf, acc_o[tt], 0, 0, 0);
      }
    }
    __syncthreads();
  }

  u16* ob = ao + (long)(b * 2048 + q0 + w * 16) * 1024 + h * 64;
#pragma unroll
  for (int r = 0; r < 4; ++r) {
    float inv = 1.f / lrow[r];
#pragma unroll
    for (int tt = 0; tt < 4; ++tt)
      ob[(long)(fg * 4 + r) * 1024 + tt * 16 + fr] = f2bf(acc_o[tt][r] * inv);
  }
}

extern "C" void kernel_launch(void* const* d_in, const int* in_sizes, int n_in,
                              void* d_out, int out_size, void* d_ws, size_t ws_size,
                              hipStream_t stream) {
  const float* x     = (const float*)d_in[0];   // [4,2048,1024]
  const float* wqkv  = (const float*)d_in[1];   // [3072,1024]
  const float* wproj = (const float*)d_in[2];   // [1024,1024]
  const float* bproj = (const float*)d_in[3];   // [1024]
  float* out = (float*)d_out;

  u16* ws    = (u16*)d_ws;
  u16* xb    = ws;                    // 8388608  : x bf16 (dead after gemm1)
  u16* wqkvb = xb + 8388608;          // 3145728  : w_qkv bf16
  u16* wpb   = wqkvb + 3145728;       // 1048576  : w_proj bf16
  u16* qkb   = wpb + 1048576;         // 16777216 : [B*N][2048] Q|K bf16
  u16* vtb   = qkb + 16777216;        // 8388608  : [bh*64+d][2048] V^T bf16
  u16* aob   = xb;                    // aliases xb (x dead before attn writes)
  // peak 37748736 u16 = 75.5 MB

  cast_f32_bf16<<<4096, 256, 0, stream>>>(x, xb);
  cast_f32_bf16<<<1536, 256, 0, stream>>>(wqkv, wqkvb);
  cast_f32_bf16<<<512, 256, 0, stream>>>(wproj, wpb);

  gemm_nt<0><<<dim3(24, 64), 256, 0, stream>>>(xb, wqkvb, qkb, vtb, nullptr, nullptr);
  attn_fused<<<dim3(32, 64), 256, 0, stream>>>(qkb, vtb, aob);
  gemm_nt<1><<<dim3(8, 64), 256, 0, stream>>>(aob, wpb, nullptr, nullptr, out, bproj);
}